// Round 1
// baseline (215.797 us; speedup 1.0000x reference)
//
#include <hip/hip_runtime.h>
#include <math.h>

// GraphLaplacian: out[b,v] = || sum_w L[v,w] * verts[b,w,:] ||_2
// L is 6000x6000 fp32 but sparse (~13 nnz/row). Strategy: scan L rows at
// HBM bandwidth (coalesced float4), collect nonzeros into LDS, then do the
// tiny SpMM against L2-resident verts.

#define NUM_V   6000
#define BATCH   32
#define ROW_F4  (NUM_V / 4)     // 1500 float4 per row
#define MAX_NNZ 1024            // max degree in this random graph is ~35; huge margin

__global__ __launch_bounds__(256, 4)
void graph_laplacian_kernel(const float* __restrict__ verts,
                            const float* __restrict__ L,
                            float* __restrict__ out) {
    __shared__ int   s_cols[MAX_NNZ];
    __shared__ float s_vals[MAX_NNZ];
    __shared__ int   s_cnt;
    __shared__ float s_acc[BATCH * 3];

    const int v = blockIdx.x;
    const int t = threadIdx.x;

    if (t == 0) s_cnt = 0;
    __syncthreads();

    // ---- Phase 1: coalesced scan of row v of L, collect nonzeros ----
    const float4* rowp = reinterpret_cast<const float4*>(L + (size_t)v * NUM_V);
    for (int i = t; i < ROW_F4; i += 256) {
        float4 q = rowp[i];
        if (q.x != 0.f) { int p = atomicAdd(&s_cnt, 1); s_cols[p] = 4*i;   s_vals[p] = q.x; }
        if (q.y != 0.f) { int p = atomicAdd(&s_cnt, 1); s_cols[p] = 4*i+1; s_vals[p] = q.y; }
        if (q.z != 0.f) { int p = atomicAdd(&s_cnt, 1); s_cols[p] = 4*i+2; s_vals[p] = q.z; }
        if (q.w != 0.f) { int p = atomicAdd(&s_cnt, 1); s_cols[p] = 4*i+3; s_vals[p] = q.w; }
    }
    __syncthreads();

    int cnt = s_cnt;
    if (cnt > MAX_NNZ) cnt = MAX_NNZ;   // safety clamp (never hit for this input)

    // ---- Phase 2: each of 96 threads owns one (batch, dim) pair ----
    if (t < BATCH * 3) {
        const int b = t / 3;
        const int d = t - 3 * b;
        const float* vb = verts + (size_t)b * (NUM_V * 3) + d;
        float acc = 0.f;
        for (int i = 0; i < cnt; ++i) {
            // s_vals[i]/s_cols[i]: same-address LDS broadcast across lanes (free)
            acc = fmaf(s_vals[i], vb[(size_t)s_cols[i] * 3], acc);
        }
        s_acc[t] = acc;
    }
    __syncthreads();

    // ---- Phase 3: norm over the 3 dims, one thread per batch ----
    if (t < BATCH) {
        float x = s_acc[3*t + 0];
        float y = s_acc[3*t + 1];
        float z = s_acc[3*t + 2];
        out[(size_t)t * NUM_V + v] = sqrtf(fmaf(x, x, fmaf(y, y, z * z)));
    }
}

extern "C" void kernel_launch(void* const* d_in, const int* in_sizes, int n_in,
                              void* d_out, int out_size, void* d_ws, size_t ws_size,
                              hipStream_t stream) {
    const float* verts = (const float*)d_in[0];   // (32, 6000, 3) fp32
    const float* L     = (const float*)d_in[1];   // (6000, 6000) fp32
    float* out         = (float*)d_out;           // (32, 6000)  fp32

    graph_laplacian_kernel<<<NUM_V, 256, 0, stream>>>(verts, L, out);
}

// Round 2
// 212.470 us; speedup vs baseline: 1.0157x; 1.0157x over previous
//
#include <hip/hip_runtime.h>
#include <math.h>

// GraphLaplacian: out[b,v] = || sum_w L[v,w] * verts[b,w,:] ||_2
// L is 6000x6000 fp32 but sparse (~13 nnz/row). One block per row:
// Phase 1 streams the row at HBM BW with a single any-nonzero branch per
// float4 pair; nonzeros are appended to a small LDS list. Phase 2 does the
// tiny SpMM against L2-resident verts; Phase 3 writes the 32 norms.

#define NUM_V   6000
#define BATCH   32
#define ROW_F4  (NUM_V / 4)     // 1500 float4 per row
#define MAX_NNZ 256             // max row degree ~35; big margin

__global__ __launch_bounds__(256, 8)
void graph_laplacian_kernel(const float* __restrict__ verts,
                            const float* __restrict__ L,
                            float* __restrict__ out) {
    __shared__ int   s_cols[MAX_NNZ];
    __shared__ float s_vals[MAX_NNZ];
    __shared__ int   s_cnt;
    __shared__ float s_acc[BATCH * 3];

    const int v = blockIdx.x;
    const int t = threadIdx.x;

    if (t == 0) s_cnt = 0;
    __syncthreads();

    // ---- Phase 1: coalesced scan of row v, 32 B per lane per iteration ----
    const float4* rowp = reinterpret_cast<const float4*>(L + (size_t)v * NUM_V);
    #pragma unroll
    for (int k = 0; k < 3; ++k) {
        const int i = k * 512 + 2 * t;          // even; i+1 valid iff i < ROW_F4
        if (i < ROW_F4) {
            float4 a = rowp[i];
            float4 b = rowp[i + 1];
            // single branch per 32 B: almost always not taken
            bool nz = (a.x != 0.f) | (a.y != 0.f) | (a.z != 0.f) | (a.w != 0.f) |
                      (b.x != 0.f) | (b.y != 0.f) | (b.z != 0.f) | (b.w != 0.f);
            if (nz) {
                const int c0 = 4 * i;
                if (a.x != 0.f) { int p = atomicAdd(&s_cnt, 1); s_cols[p] = c0;     s_vals[p] = a.x; }
                if (a.y != 0.f) { int p = atomicAdd(&s_cnt, 1); s_cols[p] = c0 + 1; s_vals[p] = a.y; }
                if (a.z != 0.f) { int p = atomicAdd(&s_cnt, 1); s_cols[p] = c0 + 2; s_vals[p] = a.z; }
                if (a.w != 0.f) { int p = atomicAdd(&s_cnt, 1); s_cols[p] = c0 + 3; s_vals[p] = a.w; }
                if (b.x != 0.f) { int p = atomicAdd(&s_cnt, 1); s_cols[p] = c0 + 4; s_vals[p] = b.x; }
                if (b.y != 0.f) { int p = atomicAdd(&s_cnt, 1); s_cols[p] = c0 + 5; s_vals[p] = b.y; }
                if (b.z != 0.f) { int p = atomicAdd(&s_cnt, 1); s_cols[p] = c0 + 6; s_vals[p] = b.z; }
                if (b.w != 0.f) { int p = atomicAdd(&s_cnt, 1); s_cols[p] = c0 + 7; s_vals[p] = b.w; }
            }
        }
    }
    __syncthreads();

    int cnt = s_cnt;
    if (cnt > MAX_NNZ) cnt = MAX_NNZ;   // safety clamp (never hit for this input)

    // ---- Phase 2: each of 96 threads owns one (batch, dim) pair ----
    if (t < BATCH * 3) {
        const int b = t / 3;
        const int d = t - 3 * b;
        const float* vb = verts + (size_t)b * (NUM_V * 3) + d;
        float acc = 0.f;
        for (int i = 0; i < cnt; ++i) {
            // s_vals[i]/s_cols[i]: same-address LDS broadcast across lanes (free)
            acc = fmaf(s_vals[i], vb[(size_t)s_cols[i] * 3], acc);
        }
        s_acc[t] = acc;
    }
    __syncthreads();

    // ---- Phase 3: norm over the 3 dims, one thread per batch ----
    if (t < BATCH) {
        float x = s_acc[3*t + 0];
        float y = s_acc[3*t + 1];
        float z = s_acc[3*t + 2];
        out[(size_t)t * NUM_V + v] = sqrtf(fmaf(x, x, fmaf(y, y, z * z)));
    }
}

extern "C" void kernel_launch(void* const* d_in, const int* in_sizes, int n_in,
                              void* d_out, int out_size, void* d_ws, size_t ws_size,
                              hipStream_t stream) {
    const float* verts = (const float*)d_in[0];   // (32, 6000, 3) fp32
    const float* L     = (const float*)d_in[1];   // (6000, 6000) fp32
    float* out         = (float*)d_out;           // (32, 6000)  fp32

    graph_laplacian_kernel<<<NUM_V, 256, 0, stream>>>(verts, L, out);
}

// Round 3
// 209.296 us; speedup vs baseline: 1.0311x; 1.0152x over previous
//
#include <hip/hip_runtime.h>
#include <math.h>

// GraphLaplacian: out[b,v] = || sum_w L[v,w] * verts[b,w,:] ||_2
// L is 6000x6000 fp32, ~13 nnz/row. One block per row.
// Phase 1: stream the row with 6 float4 loads/thread all in flight.
// Phase 2: nnz gather with 2 threads per (b,d) pair + 4-wide unroll so
//          gathers overlap instead of forming a latency chain.

#define NUM_V   6000
#define BATCH   32
#define ROW_F4  (NUM_V / 4)     // 1500 float4 per row
#define MAX_NNZ 256             // max row degree ~35; big margin

__device__ __forceinline__ void collect(float4 a, int c0,
                                        int* s_cols, float* s_vals, int* s_cnt) {
    bool nz = (a.x != 0.f) | (a.y != 0.f) | (a.z != 0.f) | (a.w != 0.f);
    if (nz) {
        if (a.x != 0.f) { int p = atomicAdd(s_cnt, 1); s_cols[p] = c0;     s_vals[p] = a.x; }
        if (a.y != 0.f) { int p = atomicAdd(s_cnt, 1); s_cols[p] = c0 + 1; s_vals[p] = a.y; }
        if (a.z != 0.f) { int p = atomicAdd(s_cnt, 1); s_cols[p] = c0 + 2; s_vals[p] = a.z; }
        if (a.w != 0.f) { int p = atomicAdd(s_cnt, 1); s_cols[p] = c0 + 3; s_vals[p] = a.w; }
    }
}

__global__ __launch_bounds__(256, 8)
void graph_laplacian_kernel(const float* __restrict__ verts,
                            const float* __restrict__ L,
                            float* __restrict__ out) {
    __shared__ int   s_cols[MAX_NNZ];
    __shared__ float s_vals[MAX_NNZ];
    __shared__ int   s_cnt;
    __shared__ float s_part[192];

    const int v = blockIdx.x;
    const int t = threadIdx.x;

    if (t == 0) s_cnt = 0;

    // ---- Phase 1: issue all 6 row loads up front (stride-256, coalesced) ----
    const float4* rowp = reinterpret_cast<const float4*>(L + (size_t)v * NUM_V);
    float4 a0 = rowp[t];
    float4 a1 = rowp[t + 256];
    float4 a2 = rowp[t + 512];
    float4 a3 = rowp[t + 768];
    float4 a4 = rowp[t + 1024];
    float4 a5 = (t < ROW_F4 - 1280) ? rowp[t + 1280] : make_float4(0.f, 0.f, 0.f, 0.f);

    __syncthreads();   // s_cnt=0 visible; overlaps with load latency

    collect(a0, 4 * t,            s_cols, s_vals, &s_cnt);
    collect(a1, 4 * (t + 256),    s_cols, s_vals, &s_cnt);
    collect(a2, 4 * (t + 512),    s_cols, s_vals, &s_cnt);
    collect(a3, 4 * (t + 768),    s_cols, s_vals, &s_cnt);
    collect(a4, 4 * (t + 1024),   s_cols, s_vals, &s_cnt);
    collect(a5, 4 * (t + 1280),   s_cols, s_vals, &s_cnt);
    __syncthreads();

    int cnt = s_cnt;
    if (cnt > MAX_NNZ) cnt = MAX_NNZ;   // safety clamp (never hit)

    // ---- Phase 2: 192 threads = 2 per (batch,dim) pair, 4-wide unrolled ----
    if (t < 192) {
        const int p = t >> 1;           // pair 0..95
        const int h = t & 1;            // half 0/1
        const int b = p / 3;
        const int d = p - 3 * b;
        const float* vb = verts + (size_t)b * (NUM_V * 3) + d;
        float acc = 0.f;
        int i = h;
        for (; i + 6 < cnt; i += 8) {
            int   c0 = s_cols[i],     c1 = s_cols[i + 2],
                  c2 = s_cols[i + 4], c3 = s_cols[i + 6];
            float w0 = s_vals[i],     w1 = s_vals[i + 2],
                  w2 = s_vals[i + 4], w3 = s_vals[i + 6];
            float x0 = vb[c0 * 3], x1 = vb[c1 * 3], x2 = vb[c2 * 3], x3 = vb[c3 * 3];
            acc = fmaf(w0, x0, fmaf(w1, x1, fmaf(w2, x2, fmaf(w3, x3, acc))));
        }
        for (; i < cnt; i += 2)
            acc = fmaf(s_vals[i], vb[(size_t)s_cols[i] * 3], acc);
        s_part[t] = acc;
    }
    __syncthreads();

    // ---- Phase 3: combine halves + dims, write norm ----
    if (t < BATCH) {
        float x = s_part[6 * t + 0] + s_part[6 * t + 1];
        float y = s_part[6 * t + 2] + s_part[6 * t + 3];
        float z = s_part[6 * t + 4] + s_part[6 * t + 5];
        out[(size_t)t * NUM_V + v] = sqrtf(fmaf(x, x, fmaf(y, y, z * z)));
    }
}

extern "C" void kernel_launch(void* const* d_in, const int* in_sizes, int n_in,
                              void* d_out, int out_size, void* d_ws, size_t ws_size,
                              hipStream_t stream) {
    const float* verts = (const float*)d_in[0];   // (32, 6000, 3) fp32
    const float* L     = (const float*)d_in[1];   // (6000, 6000) fp32
    float* out         = (float*)d_out;           // (32, 6000)  fp32

    graph_laplacian_kernel<<<NUM_V, 256, 0, stream>>>(verts, L, out);
}